// Round 14
// baseline (71.578 us; speedup 1.0000x reference)
//
#include <hip/hip_runtime.h>

#define OUT_DIM 128
#define CHUNKN 36864            // nodes per chunk -> 144 KB LDS (cap 160 KB; 128 KB proven r11)
#define PB 86                   // blocks per chunk -> grid 3*86 = 258
#define NCH_MAX 3               // ceil(2^17 / 36864) = 4 would exceed; gate N <= 3*CHUNKN

typedef int          vint4  __attribute__((ext_vector_type(4)));
typedef unsigned int vuint4 __attribute__((ext_vector_type(4)));
typedef unsigned int u32;

// Round-to-nearest bf16 of d>=0, keep low 15 bits (sign always 0).
// Order-preserving for d>=0. enc15(0)=0.
__device__ __forceinline__ u32 enc15(float d) {
    u32 b = __float_as_uint(d);
    b += 0x7FFFu + ((b >> 16) & 1u);
    return (b >> 16) & 0x7FFFu;
}

// --- kernel 1: p[i] = nodes[i]·W_theta ; meanW = mean(W_phi)
__global__ void init_kernel(float* __restrict__ p, float* __restrict__ meanW,
                            const float* __restrict__ nodes,
                            const float* __restrict__ Wt,
                            const float* __restrict__ W_phi, int n) {
    int i = blockIdx.x * blockDim.x + threadIdx.x;
    if (i < n) {
        float x = nodes[3 * i], y = nodes[3 * i + 1], z = nodes[3 * i + 2];
        p[i] = x * Wt[0] + y * Wt[1] + z * Wt[2];
    }
    if (blockIdx.x == 0 && threadIdx.x == 0) {
        float s = 0.0f;
        #pragma unroll
        for (int j = 0; j < OUT_DIM; ++j) s += W_phi[j];
        *meanW = s / (float)OUT_DIM;
    }
}

// --- kernel 2: key[e] = (row << 15) | enc15(|p[row]-p[col]|)  (row < 2^17)
__global__ void encode_kernel(const float* __restrict__ p,
                              const int* __restrict__ row,
                              const int* __restrict__ col,
                              u32* __restrict__ key, int E) {
    int t = blockIdx.x * blockDim.x + threadIdx.x;
    int base = t * 4;
    if (base >= E) return;
    if (base + 3 < E) {
        vint4 r = __builtin_nontemporal_load((const vint4*)(row + base));
        vint4 c = __builtin_nontemporal_load((const vint4*)(col + base));
        float d0 = fabsf(p[r.x] - p[c.x]);
        float d1 = fabsf(p[r.y] - p[c.y]);
        float d2 = fabsf(p[r.z] - p[c.z]);
        float d3 = fabsf(p[r.w] - p[c.w]);
        vuint4 k;
        k.x = ((u32)r.x << 15) | enc15(d0);
        k.y = ((u32)r.y << 15) | enc15(d1);
        k.z = ((u32)r.z << 15) | enc15(d2);
        k.w = ((u32)r.w << 15) | enc15(d3);
        *(vuint4*)(key + base) = k;   // regular store: keep key L2/L3-resident
    } else {
        for (int e = base; e < E; ++e)
            key[e] = ((u32)row[e] << 15) | enc15(fabsf(p[row[e]] - p[col[e]]));
    }
}

// Range filter: rel = row - chunk_base; accept if rel < CHUNKN.
// (macro param must not be named x/y/z/w — token-based preprocessor)
#define PROC(V) do { \
        u32 rx = (V.x >> 15) - cbase; if (rx < CHUNKN) atomicMax(&lds[rx], V.x & 0x7FFFu); \
        u32 ry = (V.y >> 15) - cbase; if (ry < CHUNKN) atomicMax(&lds[ry], V.y & 0x7FFFu); \
        u32 rz = (V.z >> 15) - cbase; if (rz < CHUNKN) atomicMax(&lds[rz], V.z & 0x7FFFu); \
        u32 rw = (V.w >> 15) - cbase; if (rw < CHUNKN) atomicMax(&lds[rw], V.w & 0x7FFFu); \
    } while (0)

// --- kernel 3: per-chunk LDS segmented max, 144 KB LDS, 1024 threads
// (16 waves/CU for latency hiding), grid = nch*PB. x4-unrolled vec4 stream
// (16 keys in flight/thread). Partials packed 2xu16 per u32.
__global__ __launch_bounds__(1024) void chunkmax_kernel(const u32* __restrict__ key,
                                                        u32* __restrict__ partial,
                                                        int E, int nch) {
    __shared__ u32 lds[CHUNKN];
    int c = blockIdx.x / PB;
    int b = blockIdx.x % PB;
    vuint4 zero = {0u, 0u, 0u, 0u};
    vuint4* lds4 = (vuint4*)lds;
    for (int i = threadIdx.x; i < CHUNKN / 4; i += 1024) lds4[i] = zero;
    __syncthreads();

    int G = E >> 2;                       // vec4 groups
    int per = (G + PB - 1) / PB;
    int s = b * per;
    int e = min(s + per, G);
    const vuint4* key4 = (const vuint4*)key;
    u32 cbase = (u32)c * CHUNKN;
    const int step = 1024;
    int k = s + (int)threadIdx.x;
    for (; k + 3 * step < e; k += 4 * step) {
        vuint4 a0 = key4[k];
        vuint4 a1 = key4[k + step];
        vuint4 a2 = key4[k + 2 * step];
        vuint4 a3 = key4[k + 3 * step];
        PROC(a0); PROC(a1); PROC(a2); PROC(a3);
    }
    for (; k < e; k += step) {
        vuint4 a0 = key4[k];
        PROC(a0);
    }
    if (b == PB - 1) {  // scalar tail (E % 4), once per chunk
        for (int j = (G << 2) + (int)threadIdx.x; j < E; j += step) {
            u32 v = key[j];
            u32 rel = (v >> 15) - cbase;
            if (rel < CHUNKN) atomicMax(&lds[rel], v & 0x7FFFu);
        }
    }
    __syncthreads();
    // packed writeout: u32 = lds[2j] | lds[2j+1]<<16
    u32* dst = partial + ((size_t)c * PB + b) * (CHUNKN / 2);
    for (int j = threadIdx.x; j < CHUNKN / 2; j += 1024)
        dst[j] = lds[2 * j] | (lds[2 * j + 1] << 16);
}

// --- kernel 4: reduce PB packed partials per chunk + final combine (2 nodes/thread)
__global__ void reduce_final_kernel(const float* __restrict__ prev,
                                    const u32* __restrict__ partial,
                                    const float* __restrict__ meanW,
                                    float* __restrict__ out, int n) {
    int t = blockIdx.x * blockDim.x + threadIdx.x;
    int i0 = t * 2;
    if (i0 >= n) return;
    int chunk = i0 / CHUNKN;                 // compiler magic-div
    int local = i0 - chunk * CHUNKN;         // even (CHUNKN even)
    const u32* base = partial + (size_t)chunk * PB * (CHUNKN / 2) + (local >> 1);
    u32 mlo = 0, mhi = 0;
    #pragma unroll 2
    for (int b = 0; b < PB; ++b) {
        u32 v = base[(size_t)b * (CHUNKN / 2)];
        mlo = max(mlo, v & 0xFFFFu);
        mhi = max(mhi, v >> 16);
    }
    float mw = *meanW;
    float flo = __uint_as_float(mlo << 16);  // decode bf16 (sign 0)
    float fhi = __uint_as_float(mhi << 16);
    out[i0] = 0.5f * (prev[i0] + mw * flo);
    if (i0 + 1 < n)
        out[i0 + 1] = 0.5f * (prev[i0 + 1] + mw * fhi);
}

// ---------- fallback path: global-atomic version (any size) ----------
__global__ void fb_zero_kernel(float* __restrict__ maxd, float* __restrict__ p,
                               float* __restrict__ meanW,
                               const float* __restrict__ nodes,
                               const float* __restrict__ Wt,
                               const float* __restrict__ W_phi, int n) {
    int i = blockIdx.x * blockDim.x + threadIdx.x;
    if (i < n) {
        maxd[i] = 0.0f;
        float x = nodes[3 * i], y = nodes[3 * i + 1], z = nodes[3 * i + 2];
        p[i] = x * Wt[0] + y * Wt[1] + z * Wt[2];
    }
    if (blockIdx.x == 0 && threadIdx.x == 0) {
        float s = 0.0f;
        for (int j = 0; j < OUT_DIM; ++j) s += W_phi[j];
        *meanW = s / (float)OUT_DIM;
    }
}
__global__ void fb_edge_kernel(const float* __restrict__ p,
                               const int* __restrict__ row,
                               const int* __restrict__ col,
                               float* __restrict__ maxd, int E) {
    int t = blockIdx.x * blockDim.x + threadIdx.x;
    int base = t * 4;
    if (base >= E) return;
    if (base + 3 < E) {
        vint4 r = __builtin_nontemporal_load((const vint4*)(row + base));
        vint4 c = __builtin_nontemporal_load((const vint4*)(col + base));
        atomicMax((int*)&maxd[r.x], __float_as_int(fabsf(p[r.x] - p[c.x])));
        atomicMax((int*)&maxd[r.y], __float_as_int(fabsf(p[r.y] - p[c.y])));
        atomicMax((int*)&maxd[r.z], __float_as_int(fabsf(p[r.z] - p[c.z])));
        atomicMax((int*)&maxd[r.w], __float_as_int(fabsf(p[r.w] - p[c.w])));
    } else {
        for (int e = base; e < E; ++e) {
            float d = fabsf(p[row[e]] - p[col[e]]);
            atomicMax((int*)&maxd[row[e]], __float_as_int(d));
        }
    }
}
__global__ void fb_final_kernel(const float* __restrict__ prev,
                                const float* __restrict__ maxd,
                                const float* __restrict__ meanW,
                                float* __restrict__ out, int n) {
    int i = blockIdx.x * blockDim.x + threadIdx.x;
    if (i < n) out[i] = 0.5f * (prev[i] + (*meanW) * maxd[i]);
}

extern "C" void kernel_launch(void* const* d_in, const int* in_sizes, int n_in,
                              void* d_out, int out_size, void* d_ws, size_t ws_size,
                              hipStream_t stream) {
    const float* prev    = (const float*)d_in[0];   // [N]
    const float* nodes   = (const float*)d_in[1];   // [N,3]
    const int*   row     = (const int*)d_in[2];     // [E]
    const int*   col     = (const int*)d_in[3];     // [E]
    const float* W_phi   = (const float*)d_in[4];   // [128]
    const float* W_theta = (const float*)d_in[5];   // [3]

    const int N = in_sizes[0];
    const int E = in_sizes[2];
    float* out = (float*)d_out;
    const int B = 256;

    const int nch = (N + CHUNKN - 1) / CHUNKN;      // 3 for N=100K

    // ws layout: p[N] | key[Epad] | partial[nch*PB*CHUNKN/2] | meanW
    size_t pBytes    = ((size_t)N * 4 + 15) & ~(size_t)15;
    size_t keyBytes  = (((size_t)E + 3) & ~(size_t)3) * 4;
    size_t partBytes = (size_t)nch * PB * (CHUNKN / 2) * 4;
    size_t need = pBytes + keyBytes + partBytes + 4;

    if (ws_size >= need && N <= NCH_MAX * CHUNKN && N <= (1 << 17)) {
        float* p     = (float*)d_ws;
        u32*   key   = (u32*)((char*)d_ws + pBytes);
        u32*   part  = (u32*)((char*)d_ws + pBytes + keyBytes);
        float* meanW = (float*)((char*)d_ws + pBytes + keyBytes + partBytes);

        init_kernel<<<(N + B - 1) / B, B, 0, stream>>>(p, meanW, nodes, W_theta, W_phi, N);
        int tE = (E + 3) / 4;
        encode_kernel<<<(tE + B - 1) / B, B, 0, stream>>>(p, row, col, key, E);
        chunkmax_kernel<<<nch * PB, 1024, 0, stream>>>(key, part, E, nch);
        int tN = (N + 1) / 2;
        reduce_final_kernel<<<(tN + B - 1) / B, B, 0, stream>>>(prev, part, meanW, out, N);
    } else {
        float* p     = (float*)d_ws;
        float* maxd  = (float*)d_ws + N;
        float* meanW = (float*)d_ws + 2 * (size_t)N;
        fb_zero_kernel<<<(N + B - 1) / B, B, 0, stream>>>(maxd, p, meanW, nodes, W_theta, W_phi, N);
        int tE = (E + 3) / 4;
        fb_edge_kernel<<<(tE + B - 1) / B, B, 0, stream>>>(p, row, col, maxd, E);
        fb_final_kernel<<<(N + B - 1) / B, B, 0, stream>>>(prev, maxd, meanW, out, N);
    }
}

// Round 15
// 55.096 us; speedup vs baseline: 1.2992x; 1.2992x over previous
//
#include <hip/hip_runtime.h>

#define OUT_DIM 128
#define CHUNK_LG 15
#define CHUNK (1 << CHUNK_LG)   // 32768 nodes per chunk = 128 KB LDS
#define PB 64                   // blocks per chunk; grid = 4*64 = 256 = #CUs (NO tail!)
#define NT 1024                 // threads per block: 16 waves = 4 waves/SIMD

typedef int          vint4  __attribute__((ext_vector_type(4)));
typedef unsigned int vuint4 __attribute__((ext_vector_type(4)));
typedef unsigned int u32;

// Round-to-nearest bf16 of d>=0, keep low 15 bits (sign always 0).
// Order-preserving for d>=0. enc15(0)=0.
__device__ __forceinline__ u32 enc15(float d) {
    u32 b = __float_as_uint(d);
    b += 0x7FFFu + ((b >> 16) & 1u);
    return (b >> 16) & 0x7FFFu;
}

// --- kernel 1: p[i] = nodes[i]·W_theta ; meanW = mean(W_phi)
__global__ void init_kernel(float* __restrict__ p, float* __restrict__ meanW,
                            const float* __restrict__ nodes,
                            const float* __restrict__ Wt,
                            const float* __restrict__ W_phi, int n) {
    int i = blockIdx.x * blockDim.x + threadIdx.x;
    if (i < n) {
        float x = nodes[3 * i], y = nodes[3 * i + 1], z = nodes[3 * i + 2];
        p[i] = x * Wt[0] + y * Wt[1] + z * Wt[2];
    }
    if (blockIdx.x == 0 && threadIdx.x == 0) {
        float s = 0.0f;
        #pragma unroll
        for (int j = 0; j < OUT_DIM; ++j) s += W_phi[j];
        *meanW = s / (float)OUT_DIM;
    }
}

// --- kernel 2: key[e] = (row << 15) | enc15(|p[row]-p[col]|)  (row < 2^17)
__global__ void encode_kernel(const float* __restrict__ p,
                              const int* __restrict__ row,
                              const int* __restrict__ col,
                              u32* __restrict__ key, int E) {
    int t = blockIdx.x * blockDim.x + threadIdx.x;
    int base = t * 4;
    if (base >= E) return;
    if (base + 3 < E) {
        vint4 r = __builtin_nontemporal_load((const vint4*)(row + base));
        vint4 c = __builtin_nontemporal_load((const vint4*)(col + base));
        float d0 = fabsf(p[r.x] - p[c.x]);
        float d1 = fabsf(p[r.y] - p[c.y]);
        float d2 = fabsf(p[r.z] - p[c.z]);
        float d3 = fabsf(p[r.w] - p[c.w]);
        vuint4 k;
        k.x = ((u32)r.x << 15) | enc15(d0);
        k.y = ((u32)r.y << 15) | enc15(d1);
        k.z = ((u32)r.z << 15) | enc15(d2);
        k.w = ((u32)r.w << 15) | enc15(d3);
        *(vuint4*)(key + base) = k;   // regular store: keep key L2/L3-resident
    } else {
        for (int e = base; e < E; ++e)
            key[e] = ((u32)row[e] << 15) | enc15(fabsf(p[row[e]] - p[col[e]]));
    }
}

// NOTE: macro param must not be named x/y/z/w (token-based preprocessor).
#define PROC(V) do { \
        if ((V.x >> (15 + CHUNK_LG)) == uc) atomicMax(&lds[(V.x >> 15) & (CHUNK - 1)], V.x & 0x7FFFu); \
        if ((V.y >> (15 + CHUNK_LG)) == uc) atomicMax(&lds[(V.y >> 15) & (CHUNK - 1)], V.y & 0x7FFFu); \
        if ((V.z >> (15 + CHUNK_LG)) == uc) atomicMax(&lds[(V.z >> 15) & (CHUNK - 1)], V.z & 0x7FFFu); \
        if ((V.w >> (15 + CHUNK_LG)) == uc) atomicMax(&lds[(V.w >> 15) & (CHUNK - 1)], V.w & 0x7FFFu); \
    } while (0)

// --- kernel 3: per-chunk LDS segmented max. 128 KB LDS, 1024 threads
// (16 waves = 4 waves/SIMD -> 2x the outstanding loads of r11's 512),
// grid = nch*PB = 256 = CU count (no tail block). x4-unrolled vec4 stream.
// Partials packed 2xu16 per u32.
__global__ __launch_bounds__(NT) void chunkmax_kernel(const u32* __restrict__ key,
                                                      u32* __restrict__ partial,
                                                      int E, int nch) {
    __shared__ u32 lds[CHUNK];
    int c = blockIdx.x / PB;
    int b = blockIdx.x % PB;
    vuint4 zero = {0u, 0u, 0u, 0u};
    vuint4* lds4 = (vuint4*)lds;
    for (int i = threadIdx.x; i < CHUNK / 4; i += NT) lds4[i] = zero;
    __syncthreads();

    int G = E >> 2;                       // vec4 groups
    int per = (G + PB - 1) / PB;
    int s = b * per;
    int e = min(s + per, G);
    const vuint4* key4 = (const vuint4*)key;
    u32 uc = (u32)c;
    const int step = NT;
    int k = s + (int)threadIdx.x;
    for (; k + 3 * step < e; k += 4 * step) {
        vuint4 a0 = key4[k];
        vuint4 a1 = key4[k + step];
        vuint4 a2 = key4[k + 2 * step];
        vuint4 a3 = key4[k + 3 * step];
        PROC(a0); PROC(a1); PROC(a2); PROC(a3);
    }
    for (; k < e; k += step) {
        vuint4 a0 = key4[k];
        PROC(a0);
    }
    if (b == PB - 1) {  // scalar tail (E % 4), once per chunk
        for (int j = (G << 2) + (int)threadIdx.x; j < E; j += step) {
            u32 v = key[j];
            if ((v >> (15 + CHUNK_LG)) == uc) atomicMax(&lds[(v >> 15) & (CHUNK - 1)], v & 0x7FFFu);
        }
    }
    __syncthreads();
    // packed writeout: u32 = lds[2j] | lds[2j+1]<<16
    u32* dst = partial + ((size_t)c * PB + b) * (CHUNK / 2);
    for (int j = threadIdx.x; j < CHUNK / 2; j += NT)
        dst[j] = lds[2 * j] | (lds[2 * j + 1] << 16);
}

// --- kernel 4: reduce PB packed partials per chunk + final combine (2 nodes/thread)
__global__ void reduce_final_kernel(const float* __restrict__ prev,
                                    const u32* __restrict__ partial,
                                    const float* __restrict__ meanW,
                                    float* __restrict__ out, int n) {
    int t = blockIdx.x * blockDim.x + threadIdx.x;
    int i0 = t * 2;
    if (i0 >= n) return;
    int chunk = i0 >> CHUNK_LG;
    int local = i0 & (CHUNK - 1);            // even
    const u32* base = partial + (size_t)chunk * PB * (CHUNK / 2) + (local >> 1);
    u32 mlo = 0, mhi = 0;
    #pragma unroll
    for (int b = 0; b < PB; ++b) {
        u32 v = base[(size_t)b * (CHUNK / 2)];
        mlo = max(mlo, v & 0xFFFFu);
        mhi = max(mhi, v >> 16);
    }
    float mw = *meanW;
    float flo = __uint_as_float(mlo << 16);  // decode bf16 (sign 0)
    float fhi = __uint_as_float(mhi << 16);
    out[i0] = 0.5f * (prev[i0] + mw * flo);
    if (i0 + 1 < n)
        out[i0 + 1] = 0.5f * (prev[i0 + 1] + mw * fhi);
}

// ---------- fallback path: global-atomic version (any size) ----------
__global__ void fb_zero_kernel(float* __restrict__ maxd, float* __restrict__ p,
                               float* __restrict__ meanW,
                               const float* __restrict__ nodes,
                               const float* __restrict__ Wt,
                               const float* __restrict__ W_phi, int n) {
    int i = blockIdx.x * blockDim.x + threadIdx.x;
    if (i < n) {
        maxd[i] = 0.0f;
        float x = nodes[3 * i], y = nodes[3 * i + 1], z = nodes[3 * i + 2];
        p[i] = x * Wt[0] + y * Wt[1] + z * Wt[2];
    }
    if (blockIdx.x == 0 && threadIdx.x == 0) {
        float s = 0.0f;
        for (int j = 0; j < OUT_DIM; ++j) s += W_phi[j];
        *meanW = s / (float)OUT_DIM;
    }
}
__global__ void fb_edge_kernel(const float* __restrict__ p,
                               const int* __restrict__ row,
                               const int* __restrict__ col,
                               float* __restrict__ maxd, int E) {
    int t = blockIdx.x * blockDim.x + threadIdx.x;
    int base = t * 4;
    if (base >= E) return;
    if (base + 3 < E) {
        vint4 r = __builtin_nontemporal_load((const vint4*)(row + base));
        vint4 c = __builtin_nontemporal_load((const vint4*)(col + base));
        atomicMax((int*)&maxd[r.x], __float_as_int(fabsf(p[r.x] - p[c.x])));
        atomicMax((int*)&maxd[r.y], __float_as_int(fabsf(p[r.y] - p[c.y])));
        atomicMax((int*)&maxd[r.z], __float_as_int(fabsf(p[r.z] - p[c.z])));
        atomicMax((int*)&maxd[r.w], __float_as_int(fabsf(p[r.w] - p[c.w])));
    } else {
        for (int e = base; e < E; ++e) {
            float d = fabsf(p[row[e]] - p[col[e]]);
            atomicMax((int*)&maxd[row[e]], __float_as_int(d));
        }
    }
}
__global__ void fb_final_kernel(const float* __restrict__ prev,
                                const float* __restrict__ maxd,
                                const float* __restrict__ meanW,
                                float* __restrict__ out, int n) {
    int i = blockIdx.x * blockDim.x + threadIdx.x;
    if (i < n) out[i] = 0.5f * (prev[i] + (*meanW) * maxd[i]);
}

extern "C" void kernel_launch(void* const* d_in, const int* in_sizes, int n_in,
                              void* d_out, int out_size, void* d_ws, size_t ws_size,
                              hipStream_t stream) {
    const float* prev    = (const float*)d_in[0];   // [N]
    const float* nodes   = (const float*)d_in[1];   // [N,3]
    const int*   row     = (const int*)d_in[2];     // [E]
    const int*   col     = (const int*)d_in[3];     // [E]
    const float* W_phi   = (const float*)d_in[4];   // [128]
    const float* W_theta = (const float*)d_in[5];   // [3]

    const int N = in_sizes[0];
    const int E = in_sizes[2];
    float* out = (float*)d_out;
    const int B = 256;

    const int nch = (N + CHUNK - 1) >> CHUNK_LG;    // 4 for N=100K

    // ws layout: p[N] | key[Epad] | partial[nch*PB*CHUNK/2] | meanW
    size_t pBytes    = ((size_t)N * 4 + 15) & ~(size_t)15;
    size_t keyBytes  = (((size_t)E + 3) & ~(size_t)3) * 4;
    size_t partBytes = (size_t)nch * PB * (CHUNK / 2) * 4;
    size_t need = pBytes + keyBytes + partBytes + 4;

    if (ws_size >= need && N <= (1 << 17)) {
        float* p     = (float*)d_ws;
        u32*   key   = (u32*)((char*)d_ws + pBytes);
        u32*   part  = (u32*)((char*)d_ws + pBytes + keyBytes);
        float* meanW = (float*)((char*)d_ws + pBytes + keyBytes + partBytes);

        init_kernel<<<(N + B - 1) / B, B, 0, stream>>>(p, meanW, nodes, W_theta, W_phi, N);
        int tE = (E + 3) / 4;
        encode_kernel<<<(tE + B - 1) / B, B, 0, stream>>>(p, row, col, key, E);
        chunkmax_kernel<<<nch * PB, NT, 0, stream>>>(key, part, E, nch);
        int tN = (N + 1) / 2;
        reduce_final_kernel<<<(tN + B - 1) / B, B, 0, stream>>>(prev, part, meanW, out, N);
    } else {
        float* p     = (float*)d_ws;
        float* maxd  = (float*)d_ws + N;
        float* meanW = (float*)d_ws + 2 * (size_t)N;
        fb_zero_kernel<<<(N + B - 1) / B, B, 0, stream>>>(maxd, p, meanW, nodes, W_theta, W_phi, N);
        int tE = (E + 3) / 4;
        fb_edge_kernel<<<(tE + B - 1) / B, B, 0, stream>>>(p, row, col, maxd, E);
        fb_final_kernel<<<(N + B - 1) / B, B, 0, stream>>>(prev, maxd, meanW, out, N);
    }
}